// Round 2
// baseline (1021.028 us; speedup 1.0000x reference)
//
#include <hip/hip_runtime.h>

#define BATCH   32
#define SEQ     2048
#define IN_DIM  32
#define HID     512
#define STATE   64
#define NLAYERS 4
#define NTOK    (BATCH*SEQ)          // 65536
#define EPS     1e-5f
#define KTAN    2.8853900817779268f  // 2*log2(e)

#define F4(p)  (*reinterpret_cast<float4*>(p))
#define CF4(p) (*reinterpret_cast<const float4*>(p))

__device__ __forceinline__ float fast_exp2(float x){ return __builtin_amdgcn_exp2f(x); }
__device__ __forceinline__ float fast_rcp(float x){ return __builtin_amdgcn_rcpf(x); }

// ---------------------------------------------------------------------------
// h = x @ Win + bin.  M=65536, N=512, K=32.  BM=16 rows per 256-thread block,
// each thread: 4 rows x (4 + 4) cols, dense float4 stores (16B/lane, stride 16B).
__global__ __launch_bounds__(256) void k_input(const float* __restrict__ x,
    const float* __restrict__ Win, const float* __restrict__ bin,
    float* __restrict__ h)
{
  __shared__ float xs[16][32];
  int m0 = blockIdx.x * 16;
  int tid = threadIdx.x;
  #pragma unroll
  for (int i=0;i<2;i++){
    int idx = tid + i*256;            // 0..511
    xs[idx>>5][idx&31] = x[(m0 + (idx>>5))*IN_DIM + (idx&31)];
  }
  __syncthreads();
  int tx = tid & 63, ty = tid >> 6;   // ty 0..3
  int c0 = tx*4, r0 = ty*4;
  float4 bv0 = CF4(&bin[c0]);
  float4 bv1 = CF4(&bin[c0+256]);
  float4 acc[4][2];
  #pragma unroll
  for (int i=0;i<4;i++){ acc[i][0]=bv0; acc[i][1]=bv1; }
  #pragma unroll 8
  for (int k=0;k<IN_DIM;k++){
    float4 w0 = CF4(&Win[k*HID + c0]);
    float4 w1 = CF4(&Win[k*HID + c0 + 256]);
    #pragma unroll
    for (int i=0;i<4;i++){
      float xv = xs[r0+i][k];
      acc[i][0].x = fmaf(xv, w0.x, acc[i][0].x);
      acc[i][0].y = fmaf(xv, w0.y, acc[i][0].y);
      acc[i][0].z = fmaf(xv, w0.z, acc[i][0].z);
      acc[i][0].w = fmaf(xv, w0.w, acc[i][0].w);
      acc[i][1].x = fmaf(xv, w1.x, acc[i][1].x);
      acc[i][1].y = fmaf(xv, w1.y, acc[i][1].y);
      acc[i][1].z = fmaf(xv, w1.z, acc[i][1].z);
      acc[i][1].w = fmaf(xv, w1.w, acc[i][1].w);
    }
  }
  #pragma unroll
  for (int i=0;i<4;i++){
    int m = m0 + r0 + i;
    F4(&h[m*HID + c0])       = acc[i][0];
    F4(&h[m*HID + c0 + 256]) = acc[i][1];
  }
}

// ---------------------------------------------------------------------------
// Per layer precompute: A'[j][s] = g[j]*A[j][s], GA[s]=sum_j A', BA[s]=sum_j b[j]*A.
__global__ void k_prep(const float* __restrict__ A, const float* __restrict__ g,
                       const float* __restrict__ b, float* __restrict__ Ap,
                       float* __restrict__ GA, float* __restrict__ BA)
{
  int l = blockIdx.x, s = threadIdx.x;
  const float* Al = A + l*HID*STATE;
  const float* gl = g + l*HID;
  const float* bl = b + l*HID;
  float ga=0.f, ba=0.f;
  for (int j=0;j<HID;j++){
    float a  = Al[j*STATE + s];
    float ap = gl[j]*a;
    Ap[l*HID*STATE + j*STATE + s] = ap;
    ga += ap; ba += bl[j]*a;
  }
  GA[l*STATE+s]=ga; BA[l*STATE+s]=ba;
}

// ---------------------------------------------------------------------------
// Layer-0 closed-form precompute (all from x-side weights):
//  M2[a][c] = sum_j Win[a][j]Win[c][j];  w1[a]=sum_j Win[a][j]; wb[a]=sum_j Win[a][j]bin[j]
//  sc = {sum bin, sum bin^2};  WA1[k][s]=sum_j Win[k][j] g0[j] A0[j][s];  binA[s]=sum_j bin[j] g0[j] A0[j][s]
__global__ void k_prep2(const float* __restrict__ Win, const float* __restrict__ bin,
    const float* __restrict__ A0, const float* __restrict__ g0,
    float* __restrict__ M2, float* __restrict__ w1, float* __restrict__ wb,
    float* __restrict__ sc, float* __restrict__ WA1, float* __restrict__ binA)
{
  int b = blockIdx.x, tid = threadIdx.x;
  if (b == 0){
    for (int e = tid; e < 1024; e += 256){
      int a_ = e >> 5, c_ = e & 31;
      float s_ = 0.f;
      for (int j=0;j<HID;j++) s_ = fmaf(Win[a_*HID+j], Win[c_*HID+j], s_);
      M2[e] = s_;
    }
    if (tid < 32){
      float s1=0.f, s2=0.f;
      for (int j=0;j<HID;j++){
        float w = Win[tid*HID+j];
        s1 += w; s2 = fmaf(w, bin[j], s2);
      }
      w1[tid]=s1; wb[tid]=s2;
    }
    if (tid == 32){
      float sb=0.f, b2=0.f;
      for (int j=0;j<HID;j++){ float v=bin[j]; sb+=v; b2=fmaf(v,v,b2); }
      sc[0]=sb; sc[1]=b2;
    }
  } else if (b == 1){
    for (int e = tid; e < 2048; e += 256){
      int k = e >> 6, s = e & 63;
      float acc = 0.f;
      for (int j=0;j<HID;j++) acc = fmaf(Win[k*HID+j], g0[j]*A0[j*STATE+s], acc);
      WA1[e] = acc;
    }
  } else {
    if (tid < 64){
      float acc = 0.f;
      for (int j=0;j<HID;j++) acc = fmaf(bin[j], g0[j]*A0[j*STATE+tid], acc);
      binA[tid] = acc;
    }
  }
}

// ---------------------------------------------------------------------------
// U1 directly from x (skips layer-0 ugemm), plus layer-0 LN stats.
// grid = NTOK/4 blocks x 256 threads; each wave owns one row.
__global__ __launch_bounds__(256) void k_u1(const float* __restrict__ x,
    const float* __restrict__ M2, const float* __restrict__ w1,
    const float* __restrict__ wb, const float* __restrict__ sc,
    const float* __restrict__ WA1, const float* __restrict__ binA,
    const float* __restrict__ GA, const float* __restrict__ BA,
    float* __restrict__ U, float2* __restrict__ stats)
{
  int rw = threadIdx.x >> 6;
  int lane = threadIdx.x & 63;
  int m = blockIdx.x*4 + rw;
  __shared__ float xs[4][32];
  if (lane < 32) xs[rw][lane] = x[m*IN_DIM + lane];
  __syncthreads();
  float qp = 0.f, sp = 0.f;
  if (lane < 32){
    float p = 0.f;
    #pragma unroll 8
    for (int j=0;j<32;j++) p = fmaf(M2[lane*32+j], xs[rw][j], p);
    float xv = xs[rw][lane];
    qp = xv * fmaf(2.f, wb[lane], p);
    sp = xv * w1[lane];
  }
  #pragma unroll
  for (int off=16; off; off>>=1){ qp += __shfl_xor(qp, off); sp += __shfl_xor(sp, off); }
  qp = __shfl(qp, 0); sp = __shfl(sp, 0);
  float mu  = (sp + sc[0]) * (1.f/HID);
  float msq = (qp + sc[1]) * (1.f/HID);
  float rs  = rsqrtf(fmaxf(msq - mu*mu, 0.f) + EPS);
  if (lane == 0) stats[m] = make_float2(mu, rs);
  float u = binA[lane];
  #pragma unroll 8
  for (int k=0;k<32;k++) u = fmaf(xs[rw][k], WA1[k*STATE+lane], u);
  U[m*STATE+lane] = KTAN*(rs*(u - mu*GA[lane]) + BA[lane]);
}

// ---------------------------------------------------------------------------
// U[m][s] = KTAN * ( rstd_m*(h[m]@A'[:,s] - mu_m*GA[s]) + BA[s] )  (layers 1..3)
__global__ __launch_bounds__(256) void k_ugemm(const float* __restrict__ h,
    const float2* __restrict__ stats, const float* __restrict__ Ap,
    const float* __restrict__ GA, const float* __restrict__ BA,
    float* __restrict__ U)
{
  __shared__ float hsT[32][136];   // [k][m]
  __shared__ float Bs[32][68];     // [k][n]
  int m0 = blockIdx.x * 128;
  int tid = threadIdx.x;
  int tx = tid & 15, ty = tid >> 4;
  float acc[8][4] = {};
  for (int kc=0; kc<HID; kc+=32){
    #pragma unroll
    for (int i=0;i<4;i++){
      int idx = tid + i*256;
      int mr = idx >> 3;
      int kt = idx & 7;
      float4 v = CF4(&h[(m0+mr)*HID + kc + kt*4]);
      hsT[kt*4+0][mr] = v.x;
      hsT[kt*4+1][mr] = v.y;
      hsT[kt*4+2][mr] = v.z;
      hsT[kt*4+3][mr] = v.w;
    }
    #pragma unroll
    for (int i=0;i<2;i++){
      int idx = tid + i*256;
      int kr = idx >> 4;
      int c4 = idx & 15;
      F4(&Bs[kr][c4*4]) = CF4(&Ap[(kc+kr)*STATE + c4*4]);
    }
    __syncthreads();
    #pragma unroll
    for (int kk=0;kk<32;kk++){
      float4 a0 = CF4(&hsT[kk][ty*8]);
      float4 a1 = CF4(&hsT[kk][ty*8+4]);
      float4 bv = CF4(&Bs[kk][tx*4]);
      float am[8] = {a0.x,a0.y,a0.z,a0.w,a1.x,a1.y,a1.z,a1.w};
      #pragma unroll
      for (int i=0;i<8;i++){
        acc[i][0] = fmaf(am[i], bv.x, acc[i][0]);
        acc[i][1] = fmaf(am[i], bv.y, acc[i][1]);
        acc[i][2] = fmaf(am[i], bv.z, acc[i][2]);
        acc[i][3] = fmaf(am[i], bv.w, acc[i][3]);
      }
    }
    __syncthreads();
  }
  int c0 = tx*4;
  float4 ga = CF4(&GA[c0]);
  float4 ba = CF4(&BA[c0]);
  #pragma unroll
  for (int i=0;i<8;i++){
    int m = m0 + ty*8 + i;
    float2 st = stats[m];
    float4 o;
    o.x = KTAN*(st.y*(acc[i][0] - st.x*ga.x) + ba.x);
    o.y = KTAN*(st.y*(acc[i][1] - st.x*ga.y) + ba.y);
    o.z = KTAN*(st.y*(acc[i][2] - st.x*ga.z) + ba.z);
    o.w = KTAN*(st.y*(acc[i][3] - st.x*ga.w) + ba.w);
    F4(&U[m*STATE + c0]) = o;
  }
}

// ---------------------------------------------------------------------------
// Sequential recurrence. 32 blocks x 64 threads, thread (b,s) owns one chain.
__global__ __launch_bounds__(64) void k_scan(const float* __restrict__ U,
                                             float* __restrict__ H)
{
  int b = blockIdx.x;
  int s = threadIdx.x;
  const float* Up = U + b*SEQ*STATE + s;
  float* Hp = H + b*SEQ*STATE + s;
  float g = 0.f;
  float cur[16], nxt[16];
  #pragma unroll
  for (int i=0;i<16;i++) cur[i] = Up[i*STATE];
  for (int t0=0; t0<SEQ; t0+=16){
    bool has_next = (t0+16 < SEQ);
    if (has_next){
      #pragma unroll
      for (int i=0;i<16;i++) nxt[i] = Up[(t0+16+i)*STATE];
    }
    #pragma unroll
    for (int i=0;i<16;i++){
      float e = fast_exp2(cur[i] + g);
      float r = fast_rcp(1.f + e);
      Hp[(t0+i)*STATE] = fmaf(-2.f, r, 1.f);
      g = fmaf(-2.f*KTAN, r, KTAN);
    }
    if (has_next){
      #pragma unroll
      for (int i=0;i<16;i++) cur[i] = nxt[i];
    }
  }
}

// ---------------------------------------------------------------------------
// In-place epilogue: h += H@C^T + xn*D; emits next-layer row stats.
__global__ __launch_bounds__(128) void k_yep(
    float* __restrict__ h, const float* __restrict__ Hg,
    const float* __restrict__ C, const float* __restrict__ Dl,
    const float* __restrict__ gl, const float* __restrict__ bl,
    const float2* __restrict__ stats_in, float2* __restrict__ stats_out)
{
  __shared__ float HshT[STATE][68];
  __shared__ float CshT[STATE][68];
  int m0 = blockIdx.x * 64;
  int tid = threadIdx.x;
  int tx = tid & 15, ty = tid >> 4;
  #pragma unroll
  for (int i=0;i<8;i++){
    int idx = tid + i*128;
    int mr = idx >> 4;
    int s4 = idx & 15;
    float4 v = CF4(&Hg[(m0+mr)*STATE + s4*4]);
    HshT[s4*4+0][mr] = v.x;
    HshT[s4*4+1][mr] = v.y;
    HshT[s4*4+2][mr] = v.z;
    HshT[s4*4+3][mr] = v.w;
  }
  float2 st[8];
  #pragma unroll
  for (int mi=0;mi<8;mi++) st[mi] = stats_in[m0 + ty*8 + mi];
  float sum[8] = {}, sq[8] = {};
  for (int jc=0;jc<HID;jc+=64){
    #pragma unroll
    for (int i=0;i<8;i++){
      int idx = tid + i*128;
      int jr = idx >> 4;
      int s4 = idx & 15;
      float4 v = CF4(&C[(jc+jr)*STATE + s4*4]);
      CshT[s4*4+0][jr] = v.x;
      CshT[s4*4+1][jr] = v.y;
      CshT[s4*4+2][jr] = v.z;
      CshT[s4*4+3][jr] = v.w;
    }
    __syncthreads();
    float acc[8][4] = {};
    #pragma unroll
    for (int s=0;s<STATE;s++){
      float4 cv = CF4(&CshT[s][tx*4]);
      float4 h0 = CF4(&HshT[s][ty*8]);
      float4 h1 = CF4(&HshT[s][ty*8+4]);
      float hm[8] = {h0.x,h0.y,h0.z,h0.w,h1.x,h1.y,h1.z,h1.w};
      #pragma unroll
      for (int mi=0;mi<8;mi++){
        acc[mi][0] = fmaf(hm[mi], cv.x, acc[mi][0]);
        acc[mi][1] = fmaf(hm[mi], cv.y, acc[mi][1]);
        acc[mi][2] = fmaf(hm[mi], cv.z, acc[mi][2]);
        acc[mi][3] = fmaf(hm[mi], cv.w, acc[mi][3]);
      }
    }
    int j0 = jc + tx*4;
    float4 g4 = CF4(&gl[j0]);
    float4 b4 = CF4(&bl[j0]);
    float4 d4 = CF4(&Dl[j0]);
    #pragma unroll
    for (int mi=0;mi<8;mi++){
      int m = m0 + ty*8 + mi;
      float4 hv = CF4(&h[m*HID + j0]);
      float mu = st[mi].x, rs = st[mi].y;
      float4 o;
      o.x = hv.x + acc[mi][0] + fmaf((hv.x - mu)*rs, g4.x, b4.x)*d4.x;
      o.y = hv.y + acc[mi][1] + fmaf((hv.y - mu)*rs, g4.y, b4.y)*d4.y;
      o.z = hv.z + acc[mi][2] + fmaf((hv.z - mu)*rs, g4.z, b4.z)*d4.z;
      o.w = hv.w + acc[mi][3] + fmaf((hv.w - mu)*rs, g4.w, b4.w)*d4.w;
      F4(&h[m*HID + j0]) = o;
      sum[mi] += (o.x+o.y)+(o.z+o.w);
      sq[mi]  += (o.x*o.x+o.y*o.y)+(o.z*o.z+o.w*o.w);
    }
    __syncthreads();
  }
  #pragma unroll
  for (int mi=0;mi<8;mi++){
    float s_ = sum[mi], q = sq[mi];
    #pragma unroll
    for (int off=8; off; off>>=1){
      s_ += __shfl_xor(s_, off);
      q  += __shfl_xor(q,  off);
    }
    if (tx==0){
      float mu  = s_*(1.f/HID);
      float var = q*(1.f/HID) - mu*mu;
      stats_out[m0 + ty*8 + mi] = make_float2(mu, rsqrtf(fmaxf(var,0.f)+EPS));
    }
  }
}

// ---------------------------------------------------------------------------
// Final LN (stats precomputed) on last token + MLP head.
__global__ __launch_bounds__(256) void k_head(const float* __restrict__ h,
   const float2* __restrict__ stats, const float* __restrict__ ng, const float* __restrict__ nb,
   const float* __restrict__ W1, const float* __restrict__ b1,
   const float* __restrict__ W2, const float* __restrict__ b2,
   float* __restrict__ out)
{
  int bb = blockIdx.x;
  int m = bb*SEQ + (SEQ-1);
  int tid = threadIdx.x;
  __shared__ float xs[HID];
  __shared__ float red[8];
  float2 st = stats[m];
  #pragma unroll
  for (int i=0;i<2;i++){
    int j = tid + i*256;
    float v = h[m*HID + j];
    xs[j] = fmaf((v - st.x)*st.y, ng[j], nb[j]);
  }
  __syncthreads();
  float acc = b1[tid];
  #pragma unroll 8
  for (int j=0;j<HID;j++) acc = fmaf(xs[j], W1[j*(HID/2) + tid], acc);
  float ge = 0.5f*acc*(1.f + erff(acc*0.70710678118654752f));
  float p0 = ge*W2[tid*2+0];
  float p1 = ge*W2[tid*2+1];
  #pragma unroll
  for (int off=32; off; off>>=1){ p0 += __shfl_down(p0, off); p1 += __shfl_down(p1, off); }
  int wid = tid>>6;
  if ((tid&63)==0){ red[wid*2]=p0; red[wid*2+1]=p1; }
  __syncthreads();
  if (tid==0){
    float o0=b2[0], o1=b2[1];
    #pragma unroll
    for (int w=0;w<4;w++){ o0+=red[w*2]; o1+=red[w*2+1]; }
    out[bb*2+0]=o0; out[bb*2+1]=o1;
  }
}

// ---------------------------------------------------------------------------
extern "C" void kernel_launch(void* const* d_in, const int* in_sizes, int n_in,
                              void* d_out, int out_size, void* d_ws, size_t ws_size,
                              hipStream_t stream)
{
  (void)in_sizes; (void)n_in; (void)out_size; (void)ws_size;
  const float* x   = (const float*)d_in[0];
  const float* Win = (const float*)d_in[1];
  const float* bin = (const float*)d_in[2];
  const float* A   = (const float*)d_in[3];
  const float* C   = (const float*)d_in[4];
  const float* Dv  = (const float*)d_in[5];
  const float* lng = (const float*)d_in[6];
  const float* lnb = (const float*)d_in[7];
  const float* ng  = (const float*)d_in[8];
  const float* nb  = (const float*)d_in[9];
  const float* W1  = (const float*)d_in[10];
  const float* b1  = (const float*)d_in[11];
  const float* W2  = (const float*)d_in[12];
  const float* b2  = (const float*)d_in[13];
  float* out = (float*)d_out;
  char* ws = (char*)d_ws;
  // workspace layout (bytes)
  float*  hbuf = (float*)(ws + 0);                       // 134,217,728
  float*  Ubuf = (float*)(ws + (size_t)134217728);       //  16,777,216
  float*  Hbuf = (float*)(ws + (size_t)150994944);       //  16,777,216
  float2* st0  = (float2*)(ws + (size_t)167772160);      //     524,288
  float2* st1  = (float2*)(ws + (size_t)168296448);      //     524,288
  float*  Ap   = (float*)(ws + (size_t)168820736);       //     524,288
  float*  GAb  = (float*)(ws + (size_t)169345024);       //       1,024
  float*  BAb  = (float*)(ws + (size_t)169346048);       //       1,024
  float*  M2b  = (float*)(ws + (size_t)169347072);       //       4,096
  float*  w1b  = (float*)(ws + (size_t)169351168);       //         128
  float*  wbb  = (float*)(ws + (size_t)169351296);       //         128
  float*  scb  = (float*)(ws + (size_t)169351424);       //           8
  float*  WA1b = (float*)(ws + (size_t)169351432);       //       8,192
  float*  binAb= (float*)(ws + (size_t)169359624);       //         256

  hipLaunchKernelGGL(k_prep,  dim3(NLAYERS), dim3(64),  0, stream, A, lng, lnb, Ap, GAb, BAb);
  hipLaunchKernelGGL(k_prep2, dim3(3),       dim3(256), 0, stream, Win, bin, A, lng,
      M2b, w1b, wbb, scb, WA1b, binAb);
  hipLaunchKernelGGL(k_input, dim3(NTOK/16), dim3(256), 0, stream, x, Win, bin, hbuf);
  hipLaunchKernelGGL(k_u1,    dim3(NTOK/4),  dim3(256), 0, stream, x,
      M2b, w1b, wbb, scb, WA1b, binAb, GAb, BAb, Ubuf, st0);
  float2* scur = st0; float2* snxt = st1;
  for (int l=0; l<NLAYERS; ++l){
    if (l > 0){
      hipLaunchKernelGGL(k_ugemm, dim3(NTOK/128), dim3(256), 0, stream,
          hbuf, scur, Ap + l*HID*STATE, GAb + l*STATE, BAb + l*STATE, Ubuf);
    }
    hipLaunchKernelGGL(k_scan,  dim3(BATCH),    dim3(64),  0, stream, Ubuf, Hbuf);
    hipLaunchKernelGGL(k_yep,   dim3(NTOK/64),  dim3(128), 0, stream,
        hbuf, Hbuf, C + l*HID*STATE, Dv + l*HID, lng + l*HID, lnb + l*HID, scur, snxt);
    float2* t = scur; scur = snxt; snxt = t;
  }
  hipLaunchKernelGGL(k_head, dim3(BATCH), dim3(256), 0, stream,
      hbuf, scur, ng, nb, W1, b1, W2, b2, out);
}